// Round 8
// baseline (61.801 us; speedup 1.0000x reference)
//
#include <hip/hip_runtime.h>

// SigKernel: X (32,256,8) f32, Y (32,256,8) f32 -> out (32,32) f32.
// refinement=1.0 => interpolation identity; scale=1.0 => a_ij = dot(dX[i-1], dY[j-1]).
// Goursat PDE on 256x256 grid, boundary K[i][0]=K[0][j]=1:
//   f1 = 1 + a/2 + a^2/12, f2 = 1 - a^2/12
//   K[i][j] = (K[i][j-1] + K[i-1][j])*f1 - K[i-1][j-1]*f2 ; out = K[255][255]
//
// Round-8: ONE WAVE PROCESSES TWO PAIRS (2b, 2b+1). They share the X batch
// (ax = b>>4), so one dxp register set feeds two independent K-chains -- the
// second chain's work fills the first chain's stall cycles (we are pinned at
// 1 wave/SIMD-class latency exposure otherwise). dy columns are read per-lane
// from LDS as 2x ds_read_b128 from a stride-48B column layout: lane stride
// 48B means 16-lane phases cover all 32 banks <=2-way -> conflict-free; DS
// pipe now holds only 8 insts/CU/step (2 waves/CU). Single-wave blocks ->
// no barriers at all. Zero-padded columns keep branch-free identity updates.

typedef float f32x2 __attribute__((ext_vector_type(2)));
typedef float f32x4 __attribute__((ext_vector_type(4)));

#define NCOLS 384        // col slots per pair; real incs at slots 63..317
#define COLF  12         // floats per col slot (48B stride)

static __device__ inline f32x2 fma2(f32x2 a, f32x2 b, f32x2 c) {
    return __builtin_elementwise_fma(a, b, c);
}

// dst[l] = (l==0) ? old : x[l-1]  (wave_shr:1, bound_ctrl=0). HW-verified r5-7.
static __device__ inline float dpp_shr1(float old, float x) {
    int r = __builtin_amdgcn_update_dpp(
        __float_as_int(old), __float_as_int(x),
        0x138 /* wave_shr:1 */, 0xF, 0xF, false);
    return __int_as_float(r);
}

// d = a * {b.lo, b.lo} ; d += a * {b.lo,b.lo} ; d += a * {b.hi,b.hi}
static __device__ inline void pk_mul_bl(f32x2& d, f32x2 a, f32x2 b) {
    asm("v_pk_mul_f32 %0, %1, %2 op_sel:[0,0] op_sel_hi:[1,0]"
        : "=v"(d) : "v"(a), "v"(b));
}
static __device__ inline void pk_fma_bl(f32x2& d, f32x2 a, f32x2 b) {
    asm("v_pk_fma_f32 %0, %1, %2, %0 op_sel:[0,0,0] op_sel_hi:[1,0,1]"
        : "+v"(d) : "v"(a), "v"(b));
}
static __device__ inline void pk_fma_bh(f32x2& d, f32x2 a, f32x2 b) {
    asm("v_pk_fma_f32 %0, %1, %2, %0 op_sel:[0,1,0] op_sel_hi:[1,1,1]"
        : "+v"(d) : "v"(a), "v"(b));
}

__global__ __launch_bounds__(64) void sigker_twopair(
    const float* __restrict__ X,
    const float* __restrict__ Y,
    float* __restrict__ out)
{
    const int b   = blockIdx.x;          // 0..511
    const int ax  = b >> 4;              // pairs 2b,2b+1 share this X batch
    const int byA = (b & 15) << 1;
    const int byB = byA + 1;
    const int l   = threadIdx.x;         // 0..63

    __shared__ float dYs[2][NCOLS * COLF];   // 2 x 18432 B

    const f32x4 zz = (f32x4){0, 0, 0, 0};

    // ---- zero pads: cols 0..62 and 318..383 of both planes ----
    #pragma unroll
    for (int p = 0; p < 2; ++p) {
        f32x4* Z = (f32x4*)dYs[p];           // 3 f32x4 slots per col
        if (l < 63) { Z[3*l] = zz; Z[3*l+1] = zz; Z[3*l+2] = zz; }
        const int c = 318 + l;               // 318..381
        Z[3*c] = zz; Z[3*c+1] = zz; Z[3*c+2] = zz;
        if (l < 2) {
            const int c2 = 382 + l;
            Z[3*c2] = zz; Z[3*c2+1] = zz; Z[3*c2+2] = zz;
        }
    }

    // ---- stage dY increments for both planes: inc ji at col slot ji+63 ----
    #pragma unroll
    for (int p = 0; p < 2; ++p) {
        const float* Yb = Y + (p ? byB : byA) * 2048;
        f32x4 g[10];
        const f32x4* Yv = (const f32x4*)(Yb + l * 32);
        #pragma unroll
        for (int k = 0; k < 8; ++k) g[k] = Yv[k];
        g[8] = (l < 63) ? Yv[8] : zz;
        g[9] = (l < 63) ? Yv[9] : zz;
        #pragma unroll
        for (int r = 0; r < 4; ++r) {
            const int ji = 4 * l + r;
            if (ji < 255) {
                f32x4 d0, d1;
                #pragma unroll
                for (int c = 0; c < 4; ++c) {
                    const int e = r * 8 + c;
                    d0[c] = g[(e + 8) >> 2][(e + 8) & 3] - g[e >> 2][e & 3];
                }
                #pragma unroll
                for (int c = 4; c < 8; ++c) {
                    const int e = r * 8 + c;
                    d1[c - 4] = g[(e + 8) >> 2][(e + 8) & 3] - g[e >> 2][e & 3];
                }
                f32x4* W = (f32x4*)(dYs[p] + (ji + 63) * COLF);
                W[0] = d0;
                W[1] = d1;
            }
        }
    }

    // ---- shared dx: rows 4l+1..4l+4 of X batch ax ----
    f32x2 dxp0[8], dxp1[8];   // {r0,r1}, {r2,r3} per dim
    {
        const float* Xa = X + ax * 2048;
        f32x4 f[10];
        const f32x4* Xv = (const f32x4*)(Xa + l * 32);
        #pragma unroll
        for (int k = 0; k < 8; ++k) f[k] = Xv[k];
        f[8] = (l < 63) ? Xv[8] : zz;
        f[9] = (l < 63) ? Xv[9] : zz;
        #pragma unroll
        for (int c = 0; c < 8; ++c) {
            const float e0 = f[(c)      >> 2][(c)      & 3];
            const float e1 = f[(8 + c)  >> 2][(8 + c)  & 3];
            const float e2 = f[(16 + c) >> 2][(16 + c) & 3];
            const float e3 = f[(24 + c) >> 2][(24 + c) & 3];
            const float e4 = f[(32 + c) >> 2][(32 + c) & 3];
            dxp0[c] = (f32x2){e1 - e0, e2 - e1};
            dxp1[c] = (f32x2){e3 - e2, e4 - e3};
        }
    }
    // Single-wave block: in-order DS pipe + compiler waitcnt order the
    // staging writes before the reads below. No barrier needed.

    const f32x2 C12  = { 1.0f / 12.0f,  1.0f / 12.0f};
    const f32x2 CN12 = {-1.0f / 12.0f, -1.0f / 12.0f};
    const f32x2 CH   = { 0.5f, 0.5f};
    const f32x2 C1   = { 1.0f, 1.0f};

    auto ldcol = [](const float* p, f32x2 d[4]) {
        const f32x4* q = (const f32x4*)p;
        const f32x4 t0 = q[0], t1 = q[1];
        d[0] = __builtin_shufflevector(t0, t0, 0, 1);
        d[1] = __builtin_shufflevector(t0, t0, 2, 3);
        d[2] = __builtin_shufflevector(t1, t1, 0, 1);
        d[3] = __builtin_shufflevector(t1, t1, 2, 3);
    };

    auto factors = [&](const f32x2 dy[4], f32x2& f1a, f32x2& f1b,
                       f32x2& f2a, f32x2& f2b) {
        f32x2 a01, a23;
        pk_mul_bl(a01, dxp0[0], dy[0]);  pk_mul_bl(a23, dxp1[0], dy[0]);
        pk_fma_bh(a01, dxp0[1], dy[0]);  pk_fma_bh(a23, dxp1[1], dy[0]);
        pk_fma_bl(a01, dxp0[2], dy[1]);  pk_fma_bl(a23, dxp1[2], dy[1]);
        pk_fma_bh(a01, dxp0[3], dy[1]);  pk_fma_bh(a23, dxp1[3], dy[1]);
        pk_fma_bl(a01, dxp0[4], dy[2]);  pk_fma_bl(a23, dxp1[4], dy[2]);
        pk_fma_bh(a01, dxp0[5], dy[2]);  pk_fma_bh(a23, dxp1[5], dy[2]);
        pk_fma_bl(a01, dxp0[6], dy[3]);  pk_fma_bl(a23, dxp1[6], dy[3]);
        pk_fma_bh(a01, dxp0[7], dy[3]);  pk_fma_bh(a23, dxp1[7], dy[3]);
        const f32x2 q01 = a01 * a01, q23 = a23 * a23;
        f1a = fma2(q01, C12, fma2(a01, CH, C1));
        f1b = fma2(q23, C12, fma2(a23, CH, C1));
        f2a = fma2(q01, CN12, C1);
        f2b = fma2(q23, CN12, C1);
    };

    float KA0 = 1.0f, KA1 = 1.0f, KA2 = 1.0f, KA3 = 1.0f, updA = 1.0f;
    float KB0 = 1.0f, KB1 = 1.0f, KB2 = 1.0f, KB3 = 1.0f, updB = 1.0f;
    f32x2 f1aA, f1bA, f2aA, f2bA;
    f32x2 f1aB, f1bB, f2aB, f2bB;

    // dy(step s) lives at col slot (s + 62 - l); start pointers at step 1.
    const float* pa = dYs[0] + (63 - l) * COLF;
    const float* pb = dYs[1] + (63 - l) * COLF;
    {
        f32x2 dyA[4], dyB[4];
        ldcol(pa, dyA);
        ldcol(pb, dyB);
        factors(dyA, f1aA, f1bA, f2aA, f2bA);
        factors(dyB, f1aB, f1bB, f2aB, f2bB);
    }
    pa += COLF;
    pb += COLF;

    #pragma unroll 2
    for (int s = 1; s <= 318; ++s) {
        // Issue next column loads first (latency hidden under recurrences).
        f32x2 nA[4], nB[4];
        ldcol(pa, nA);
        ldcol(pb, nB);
        pa += COLF;
        pb += COLF;

        // ---- recurrence step s, pair A ----
        {
            const float up = dpp_shr1(1.0f, KA3);
            const float t0 = updA * f2aA.x;
            const float t1 = KA0  * f2aA.y;
            const float t2 = KA1  * f2bA.x;
            const float t3 = KA2  * f2bA.y;
            const float c0 = fmaf(KA0, f1aA.x, -t0);
            const float c1 = fmaf(KA1, f1aA.y, -t1);
            const float c2 = fmaf(KA2, f1bA.x, -t2);
            const float c3 = fmaf(KA3, f1bA.y, -t3);
            const float k0 = fmaf(up, f1aA.x, c0);
            const float k1 = fmaf(k0, f1aA.y, c1);
            const float k2 = fmaf(k1, f1bA.x, c2);
            const float k3 = fmaf(k2, f1bA.y, c3);
            updA = up; KA0 = k0; KA1 = k1; KA2 = k2; KA3 = k3;
        }
        // ---- recurrence step s, pair B (independent chain) ----
        {
            const float up = dpp_shr1(1.0f, KB3);
            const float t0 = updB * f2aB.x;
            const float t1 = KB0  * f2aB.y;
            const float t2 = KB1  * f2bB.x;
            const float t3 = KB2  * f2bB.y;
            const float c0 = fmaf(KB0, f1aB.x, -t0);
            const float c1 = fmaf(KB1, f1aB.y, -t1);
            const float c2 = fmaf(KB2, f1bB.x, -t2);
            const float c3 = fmaf(KB3, f1bB.y, -t3);
            const float k0 = fmaf(up, f1aB.x, c0);
            const float k1 = fmaf(k0, f1aB.y, c1);
            const float k2 = fmaf(k1, f1bB.x, c2);
            const float k3 = fmaf(k2, f1bB.y, c3);
            updB = up; KB0 = k0; KB1 = k1; KB2 = k2; KB3 = k3;
        }

        // ---- factors for step s+1 (consume the loads issued above) ----
        factors(nA, f1aA, f1bA, f2aA, f2bA);
        factors(nB, f1aB, f1bB, f2aB, f2bB);
    }

    // Row 255 = lane 63, local r=2; last real update at s=318 (col 255).
    if (l == 63) {
        out[2 * b]     = KA2;
        out[2 * b + 1] = KB2;
    }
}

extern "C" void kernel_launch(void* const* d_in, const int* in_sizes, int n_in,
                              void* d_out, int out_size, void* d_ws, size_t ws_size,
                              hipStream_t stream)
{
    const float* X = (const float*)d_in[0];
    const float* Y = (const float*)d_in[1];
    float* out = (float*)d_out;
    (void)in_sizes; (void)n_in; (void)out_size; (void)d_ws; (void)ws_size;

    sigker_twopair<<<dim3(512), dim3(64), 0, stream>>>(X, Y, out);
}

// Round 9
// 61.663 us; speedup vs baseline: 1.0022x; 1.0022x over previous
//
#include <hip/hip_runtime.h>

// SigKernel: X (32,256,8) f32, Y (32,256,8) f32 -> out (32,32) f32.
// refinement=1.0 => interpolation identity; scale=1.0 => a_ij = dot(dX[i-1], dY[j-1]).
// Goursat PDE on 256x256 grid, boundary K[i][0]=K[0][j]=1:
//   f1 = 1 + a/2 + a^2/12, f2 = 1 - a^2/12
//   K[i][j] = (K[i][j-1] + K[i-1][j])*f1 - K[i-1][j-1]*f2 ; out = K[255][255]
//
// Round-9: TWO waves per pair (2048 waves -> 2/SIMD TLP; r5-r8 were pinned at
// 1/SIMD with ~50% stall exposure). Row strips:
//   wave0: rows 1..128  (lane l: rows 2l+1, 2l+2); lane63's K1 = row 128.
//   wave1: rows 129..255 (lane l: rows 129+2l, 130+2l; lane63 row-256 dx=0).
// Wave1 lags 3 chunks (33 steps/chunk); row-128 crosses via an unwrapped LDS
// ring: wave0 writes ring[s]=K1 (lane63; other lanes write a dump region so
// no exec masking needed); wave1 lane0 takes ring[tau+63] as the dpp 'old'.
// dy columns travel by dpp wave_shr:1 with ping-pong sets: the broadcast
// ds_read_b128 pair loads inc[s+1] directly into the set that becomes the
// next dpp destination (period-3 rotation, no rotate movs, no cndmasks).
// Zero-padded inc keeps the branch-free identity-update invariant; tail
// (col>255) corruption is contained (never feeds a real cell; both waves'
// last real update is exactly step 318).

typedef float f32x4 __attribute__((ext_vector_type(4)));

#define CHUNK 33
#define NCH   10          // 9 full chunks + 1 partial (7 triples = 21 steps)
#define LAG   3
#define NSS   (NCH + LAG) // 13 supersteps
// LDS float offsets
#define INC_F  0          // 320 cols x 8 floats (zero-padded from col 255)
#define RING_F 2560       // 384 floats, slot = wave0 step s (no wrap)
#define DUMP_F 2944       // 384 floats, write sink for lanes 0..62
#define LDS_F  3328

#define C12f 0.0833333333f

// dst[l] = (l==0) ? old : x[l-1]   (v_mov_b32_dpp wave_shr:1, bound_ctrl=0
// keeps 'old' at lane 0). HW-verified rounds 5-8.
static __device__ inline float dpp_shr1(float old, float x) {
    int r = __builtin_amdgcn_update_dpp(
        __float_as_int(old), __float_as_int(x), 0x138, 0xF, 0xF, false);
    return __int_as_float(r);
}

__global__ __launch_bounds__(128) void sigker_pipe(
    const float* __restrict__ X,
    const float* __restrict__ Y,
    float* __restrict__ out)
{
    const int pair = blockIdx.x;          // 0..1023
    const int ax = pair >> 5, by = pair & 31;
    const int tid = threadIdx.x;
    const int w = tid >> 6;               // 0: top strip, 1: bottom strip
    const int l = tid & 63;

    __shared__ float lds[LDS_F];

    // ---- stage dY increments (both waves cooperate), zero the pads ----
    {
        f32x4* Z = (f32x4*)lds;           // INC region = vec4 slots 0..639
        Z[510 + tid] = (f32x4){0, 0, 0, 0};            // slots 510..637
        if (tid < 2) Z[638 + tid] = (f32x4){0, 0, 0, 0};

        const float* Yb = Y + by * 2048;
        const f32x4* Yv = (const f32x4*)(Yb + tid * 16);
        f32x4 g[6];
        #pragma unroll
        for (int k = 0; k < 4; ++k) g[k] = Yv[k];
        g[4] = (tid < 127) ? Yv[4] : (f32x4){0, 0, 0, 0};
        g[5] = (tid < 127) ? Yv[5] : (f32x4){0, 0, 0, 0};
        #pragma unroll
        for (int r = 0; r < 2; ++r) {
            const int ji = 2 * tid + r;
            if (ji < 255) {
                f32x4 d0, d1;
                #pragma unroll
                for (int c = 0; c < 4; ++c) {
                    const int e = r * 8 + c;
                    d0[c] = g[(e + 8) >> 2][(e + 8) & 3] - g[e >> 2][e & 3];
                }
                #pragma unroll
                for (int c = 4; c < 8; ++c) {
                    const int e = r * 8 + c;
                    d1[c - 4] = g[(e + 8) >> 2][(e + 8) & 3] - g[e >> 2][e & 3];
                }
                f32x4* W = (f32x4*)&lds[INC_F + ji * 8];
                W[0] = d0; W[1] = d1;
            }
        }
    }

    // ---- per-wave dx (2 rows/lane) ----
    float dx0[8], dx1[8];
    {
        const float* Xa = X + ax * 2048 + (w ? 1024 : 0);
        const f32x4* Xv = (const f32x4*)(Xa + l * 16);
        const bool tail = (w == 1 && l == 63);   // row 256 doesn't exist
        f32x4 f[6];
        #pragma unroll
        for (int k = 0; k < 4; ++k) f[k] = Xv[k];
        f[4] = tail ? (f32x4){0, 0, 0, 0} : Xv[4];
        f[5] = tail ? (f32x4){0, 0, 0, 0} : Xv[5];
        #pragma unroll
        for (int c = 0; c < 8; ++c) {
            const float e0 = f[c >> 2][c & 3];
            const float e1 = f[(8 + c) >> 2][(8 + c) & 3];
            const float e2 = f[(16 + c) >> 2][(16 + c) & 3];
            dx0[c] = e1 - e0;
            dx1[c] = tail ? 0.0f : (e2 - e1);
        }
    }
    __syncthreads();

    // ---- state init (step 1) ----
    const f32x4* incv = (const f32x4*)&lds[INC_F];
    const bool isL0 = (l == 0);
    const f32x4 zz = (f32x4){0, 0, 0, 0};

    f32x4 Aa, Ab, Ba, Bb, Ca, Cb;     // rotation sets: dy / inject / loading
    { const f32x4 i0 = incv[0], i1 = incv[1];   // inc[0] = column 1
      Aa = isL0 ? i0 : zz;  Ab = isL0 ? i1 : zz; }
    Ba = incv[2]; Bb = incv[3];       // inc[1], injected at end of step 1
    const f32x4* bcp = incv + 4;      // step s loads inc[s+1]; s=1 -> inc[2]

    float f1x, f1y, f2x, f2y;
#define FACTORS(CUa, CUb) do {                                               \
    float a0_, a1_;                                                          \
    a0_ = dx0[0] * CUa[0];             a1_ = dx1[0] * CUa[0];                \
    a0_ = fmaf(dx0[1], CUa[1], a0_);   a1_ = fmaf(dx1[1], CUa[1], a1_);      \
    a0_ = fmaf(dx0[2], CUa[2], a0_);   a1_ = fmaf(dx1[2], CUa[2], a1_);      \
    a0_ = fmaf(dx0[3], CUa[3], a0_);   a1_ = fmaf(dx1[3], CUa[3], a1_);      \
    a0_ = fmaf(dx0[4], CUb[0], a0_);   a1_ = fmaf(dx1[4], CUb[0], a1_);      \
    a0_ = fmaf(dx0[5], CUb[1], a0_);   a1_ = fmaf(dx1[5], CUb[1], a1_);      \
    a0_ = fmaf(dx0[6], CUb[2], a0_);   a1_ = fmaf(dx1[6], CUb[2], a1_);      \
    a0_ = fmaf(dx0[7], CUb[3], a0_);   a1_ = fmaf(dx1[7], CUb[3], a1_);      \
    const float q0_ = a0_ * a0_, q1_ = a1_ * a1_;                            \
    f1x = fmaf(q0_, C12f, fmaf(a0_, 0.5f, 1.0f));                            \
    f1y = fmaf(q1_, C12f, fmaf(a1_, 0.5f, 1.0f));                            \
    f2x = fmaf(q0_, -C12f, 1.0f);                                            \
    f2y = fmaf(q1_, -C12f, 1.0f);                                            \
} while (0)

    FACTORS(Aa, Ab);                  // factors for step 1

    float K0 = 1.0f, K1 = 1.0f, upd = 1.0f;
    float rgA = 1.0f, rgB = 1.0f, rgC = 1.0f;

    // ring cursors (LDS addrspace pointers, 32-bit adds)
    float* wptr = &lds[(l == 63 ? RING_F : DUMP_F + l)] + 1;  // slot s, s=1..
    const float* rptr2 = &lds[RING_F];                        // set at preload

    // One step. CU=current dy; INJ=holds inc[s], becomes new dy (dpp dst);
    // LD=free set, receives inc[s+1]. RGU = ring value for this step (w1);
    // RGL = reg receiving the 2-ahead ring prefetch.
#define STEP(CUa, CUb, INJa, INJb, LDa, LDb, RGU, RGL, ISW1) do {            \
    LDa = bcp[0]; LDb = bcp[1]; bcp += 2;          /* inc[s+1] broadcast */  \
    if (ISW1) { RGL = *rptr2; rptr2 += 1; }        /* ring[tau+65] */        \
    const float up_ = dpp_shr1(ISW1 ? RGU : 1.0f, K1);                       \
    const float t0_ = upd * f2x;                                             \
    const float t1_ = K0  * f2y;                                             \
    const float c0_ = fmaf(K0, f1x, -t0_);                                   \
    const float c1_ = fmaf(K1, f1y, -t1_);                                   \
    const float k0_ = fmaf(up_, f1x, c0_);                                   \
    const float k1_ = fmaf(k0_, f1y, c1_);                                   \
    upd = up_; K0 = k0_; K1 = k1_;                                           \
    if (!ISW1) { *wptr = k1_; wptr += 1; }         /* ring[s] = row-128 */   \
    /* transport: INJ <- lane-shifted CU; lane0 keeps INJ (= inc[s]) */      \
    INJa[0] = dpp_shr1(INJa[0], CUa[0]); INJa[1] = dpp_shr1(INJa[1], CUa[1]);\
    INJa[2] = dpp_shr1(INJa[2], CUa[2]); INJa[3] = dpp_shr1(INJa[3], CUa[3]);\
    INJb[0] = dpp_shr1(INJb[0], CUb[0]); INJb[1] = dpp_shr1(INJb[1], CUb[1]);\
    INJb[2] = dpp_shr1(INJb[2], CUb[2]); INJb[3] = dpp_shr1(INJb[3], CUb[3]);\
    FACTORS(INJa, INJb);                           /* factors for s+1 */     \
} while (0)

    // ---- superstep pipeline: 13 barriers total ----
    for (int ss = 0; ss < NSS; ++ss) {
        if (w == 0) {
            if (ss < NCH) {
                const int ntr = (ss == NCH - 1) ? 7 : 11;
                #pragma unroll 1
                for (int t = 0; t < ntr; ++t) {
                    STEP(Aa, Ab, Ba, Bb, Ca, Cb, rgA, rgC, 0);
                    STEP(Ba, Bb, Ca, Cb, Aa, Ab, rgB, rgA, 0);
                    STEP(Ca, Cb, Aa, Ab, Ba, Bb, rgC, rgB, 0);
                }
            }
        } else {
            if (ss >= LAG) {
                if (ss == LAG) {
                    // tau=1 needs ring[64] (= K[128][1]); prefetch 2 ahead.
                    rgA = lds[RING_F + 64];
                    rgB = lds[RING_F + 65];
                    rptr2 = &lds[RING_F + 66];
                }
                const int ntr = (ss == NSS - 1) ? 7 : 11;
                #pragma unroll 1
                for (int t = 0; t < ntr; ++t) {
                    STEP(Aa, Ab, Ba, Bb, Ca, Cb, rgA, rgC, 1);
                    STEP(Ba, Bb, Ca, Cb, Aa, Ab, rgB, rgA, 1);
                    STEP(Ca, Cb, Aa, Ab, Ba, Bb, rgC, rgB, 1);
                }
            }
        }
        __syncthreads();
    }

    // Row 255 = wave1 lane 63 first row; last real update at tau=318 (col 255).
    if (w == 1 && l == 63) out[pair] = K0;

#undef STEP
#undef FACTORS
}

extern "C" void kernel_launch(void* const* d_in, const int* in_sizes, int n_in,
                              void* d_out, int out_size, void* d_ws, size_t ws_size,
                              hipStream_t stream)
{
    const float* X = (const float*)d_in[0];
    const float* Y = (const float*)d_in[1];
    float* out = (float*)d_out;
    (void)in_sizes; (void)n_in; (void)out_size; (void)d_ws; (void)ws_size;

    sigker_pipe<<<dim3(32 * 32), dim3(128), 0, stream>>>(X, Y, out);
}

// Round 10
// 39.169 us; speedup vs baseline: 1.5778x; 1.5743x over previous
//
#include <hip/hip_runtime.h>

// SigKernel: X (32,256,8) f32, Y (32,256,8) f32 -> out (32,32) f32.
// refinement=1.0 => interpolation identity; scale=1.0 => a_ij = dot(dX[i-1], dY[j-1]).
// Goursat PDE on 256x256 grid, boundary K[i][0]=K[0][j]=1:
//   f1 = 1 + a/2 + a^2/12, f2 = 1 - a^2/12
//   K[i][j] = (K[i][j-1] + K[i-1][j])*f1 - K[i-1][j-1]*f2 ; out = K[255][255]
//
// 1 wave per pair, lane l owns rows 4l+1..4l+4, skewed march (step s, lane l
// -> col j = s-l), branch-free edges via zero-padded dy (r5-verified).
// Round-10: DISTANCE-2 SOFTWARE PIPELINE -- iter s runs recurrence(s) with
// factors built two iterations ago, and builds factors(s+2) from dy(s+2)
// loaded at iter s-1. Three rotating dy/factor sets, hand-rotated by a
// 3-unrolled macro (318 = 3*106). Dots use op_sel v_pk_fma broadcasts on dy
// loaded as f32x2 pair-halves (stride-9 b32: conflict-free, no packing movs),
// split into two accumulator chains (latency ~16cy) + one pk_add.

typedef float f32x2 __attribute__((ext_vector_type(2)));
typedef float f32x4 __attribute__((ext_vector_type(4)));

#define MM   255
#define DYST 9            // odd float stride -> conflict-free b32 LDS reads
#define DYSZ 3456         // max read idx 3454 (lane0, s=318 loads dy(321))

static __device__ inline f32x2 fma2(f32x2 a, f32x2 b, f32x2 c) {
    return __builtin_elementwise_fma(a, b, c);
}

// dst[l] = (l==0) ? old : x[l-1]  (wave_shr:1, bound_ctrl=0). HW-verified r5-r9.
static __device__ inline float dpp_shr1(float old, float x) {
    int r = __builtin_amdgcn_update_dpp(
        __float_as_int(old), __float_as_int(x), 0x138, 0xF, 0xF, false);
    return __int_as_float(r);
}

// Packed ops with op_sel broadcast of one 32-bit half of src1 (r7-verified).
static __device__ inline void pk_mul_bl(f32x2& d, f32x2 a, f32x2 b) {
    asm("v_pk_mul_f32 %0, %1, %2 op_sel:[0,0] op_sel_hi:[1,0]"
        : "=v"(d) : "v"(a), "v"(b));
}
static __device__ inline void pk_fma_bl(f32x2& d, f32x2 a, f32x2 b) {
    asm("v_pk_fma_f32 %0, %1, %2, %0 op_sel:[0,0,0] op_sel_hi:[1,0,1]"
        : "+v"(d) : "v"(a), "v"(b));
}
static __device__ inline void pk_fma_bh(f32x2& d, f32x2 a, f32x2 b) {
    asm("v_pk_fma_f32 %0, %1, %2, %0 op_sel:[0,1,0] op_sel_hi:[1,1,1]"
        : "+v"(d) : "v"(a), "v"(b));
}

struct Fset { f32x2 f1a, f1b, f2a, f2b; };

__global__ __launch_bounds__(64) void sigker_pipe2(
    const float* __restrict__ X,
    const float* __restrict__ Y,
    float* __restrict__ out)
{
    const int pair = blockIdx.x;      // 0..1023
    const int ax = pair >> 5;
    const int by = pair & 31;
    const int l  = threadIdx.x;       // 0..63

    __shared__ float dYs[DYSZ];

    const float* Xa = X + ax * 2048;
    const float* Yb = Y + by * 2048;

    // Zero-fill (vec4), then stage real dY increments at (ji+63)*9 + c.
    {
        f32x4* dz = (f32x4*)dYs;
        #pragma unroll
        for (int v = l; v < DYSZ / 4; v += 64) dz[v] = (f32x4){0, 0, 0, 0};
    }
    __syncthreads();
    for (int v = l; v < MM * 8; v += 64) {
        const int j = v >> 3, c = v & 7;
        dYs[(j + 63) * DYST + c] = Yb[(j + 1) * 8 + c] - Yb[j * 8 + c];
    }

    // dx rows 4l+1..4l+4: dxp0[c]={r0,r1}, dxp1[c]={r2,r3} per dim c.
    f32x2 dxp0[8], dxp1[8];
    {
        f32x4 f[10];
        const f32x4* Xv = (const f32x4*)(Xa + l * 32);
        #pragma unroll
        for (int k = 0; k < 8; ++k) f[k] = Xv[k];
        f[8] = (l < 63) ? Xv[8] : (f32x4){0, 0, 0, 0};
        f[9] = (l < 63) ? Xv[9] : (f32x4){0, 0, 0, 0};
        #pragma unroll
        for (int c = 0; c < 8; ++c) {
            const float e0 = f[(c)      >> 2][(c)      & 3];
            const float e1 = f[(8 + c)  >> 2][(8 + c)  & 3];
            const float e2 = f[(16 + c) >> 2][(16 + c) & 3];
            const float e3 = f[(24 + c) >> 2][(24 + c) & 3];
            const float e4 = f[(32 + c) >> 2][(32 + c) & 3];
            dxp0[c] = (f32x2){e1 - e0, e2 - e1};
            dxp1[c] = (f32x2){e3 - e2, e4 - e3};
        }
    }
    __syncthreads();

    const f32x2 C12  = { 1.0f / 12.0f,  1.0f / 12.0f};
    const f32x2 CN12 = {-1.0f / 12.0f, -1.0f / 12.0f};
    const f32x2 CH   = { 0.5f, 0.5f};
    const f32x2 C1   = { 1.0f, 1.0f};

    // dy(s) lives at dYs[base + (s-1)*9 .. +7], base = (63-l)*9.
    const int base = (63 - l) * DYST;

    // D[k] = {dy_{2k}, dy_{2k+1}} as an aligned VGPR pair (asm "v").
#define LOADDY(D, P) do {                                                    \
    D[0].x = (P)[0]; D[0].y = (P)[1];                                        \
    D[1].x = (P)[2]; D[1].y = (P)[3];                                        \
    D[2].x = (P)[4]; D[2].y = (P)[5];                                        \
    D[3].x = (P)[6]; D[3].y = (P)[7];                                        \
} while (0)

    // Build factor set FB from dy set D (split-accumulator dots + op_sel).
#define BUILD(FB, D) do {                                                    \
    f32x2 A0_, A1_, B0_, B1_;                                                \
    pk_mul_bl(A0_, dxp0[0], D[0]);  pk_mul_bl(B0_, dxp1[0], D[0]);           \
    pk_fma_bh(A0_, dxp0[1], D[0]);  pk_fma_bh(B0_, dxp1[1], D[0]);           \
    pk_fma_bl(A0_, dxp0[2], D[1]);  pk_fma_bl(B0_, dxp1[2], D[1]);           \
    pk_fma_bh(A0_, dxp0[3], D[1]);  pk_fma_bh(B0_, dxp1[3], D[1]);           \
    pk_mul_bl(A1_, dxp0[4], D[2]);  pk_mul_bl(B1_, dxp1[4], D[2]);           \
    pk_fma_bh(A1_, dxp0[5], D[2]);  pk_fma_bh(B1_, dxp1[5], D[2]);           \
    pk_fma_bl(A1_, dxp0[6], D[3]);  pk_fma_bl(B1_, dxp1[6], D[3]);           \
    pk_fma_bh(A1_, dxp0[7], D[3]);  pk_fma_bh(B1_, dxp1[7], D[3]);           \
    const f32x2 a01_ = A0_ + A1_;                                            \
    const f32x2 a23_ = B0_ + B1_;                                            \
    const f32x2 q01_ = a01_ * a01_, q23_ = a23_ * a23_;                      \
    FB.f1a = fma2(q01_, C12, fma2(a01_, CH, C1));                            \
    FB.f1b = fma2(q23_, C12, fma2(a23_, CH, C1));                            \
    FB.f2a = fma2(q01_, CN12, C1);                                           \
    FB.f2b = fma2(q23_, CN12, C1);                                           \
} while (0)

    // One step: load dy(s+3) into DLD, recurrence(s) with FU,
    // build factors(s+2) into FB from DCS (= dy(s+2), loaded last iter).
#define STEP(DLD, DCS, FU, FB) do {                                          \
    LOADDY(DLD, pld); pld += DYST;                                           \
    const float up_ = dpp_shr1(1.0f, K3);                                    \
    const float t0_ = upd * FU.f2a.x;                                        \
    const float t1_ = K0  * FU.f2a.y;                                        \
    const float t2_ = K1  * FU.f2b.x;                                        \
    const float t3_ = K2  * FU.f2b.y;                                        \
    const float c0_ = fmaf(K0, FU.f1a.x, -t0_);                              \
    const float c1_ = fmaf(K1, FU.f1a.y, -t1_);                              \
    const float c2_ = fmaf(K2, FU.f1b.x, -t2_);                              \
    const float c3_ = fmaf(K3, FU.f1b.y, -t3_);                              \
    const float k0_ = fmaf(up_, FU.f1a.x, c0_);                              \
    const float k1_ = fmaf(k0_, FU.f1a.y, c1_);                              \
    const float k2_ = fmaf(k1_, FU.f1b.x, c2_);                              \
    const float k3_ = fmaf(k2_, FU.f1b.y, c3_);                              \
    upd = up_; K0 = k0_; K1 = k1_; K2 = k2_; K3 = k3_;                       \
    BUILD(FB, DCS);                                                          \
} while (0)

    f32x2 DA[4], DB[4], DC[4];
    Fset F0, F1, F2;
    float K0 = 1.0f, K1 = 1.0f, K2 = 1.0f, K3 = 1.0f, upd = 1.0f;

    // Prologue: dy(1)->DB, dy(2)->DC, dy(3)->DA; factors(1)->F0, (2)->F1.
    LOADDY(DB, dYs + base);
    LOADDY(DC, dYs + base + DYST);
    LOADDY(DA, dYs + base + 2 * DYST);
    BUILD(F0, DB);
    BUILD(F1, DC);
    const float* pld = dYs + base + 3 * DYST;   // iter s=1 loads dy(4)

    // 318 steps = 106 x 3, role rotation period 3:
    //  s%3==1: Dld=DB Dcs=DA Fuse=F0 Fbld=F2
    //  s%3==2: Dld=DC Dcs=DB Fuse=F1 Fbld=F0
    //  s%3==0: Dld=DA Dcs=DC Fuse=F2 Fbld=F1
    #pragma unroll 1
    for (int it = 0; it < 106; ++it) {
        STEP(DB, DA, F0, F2);
        STEP(DC, DB, F1, F0);
        STEP(DA, DC, F2, F1);
    }

    // Row 255 = lane 63, local r=2; last real update at s=318 (j=255).
    if (l == 63) out[pair] = K2;

#undef STEP
#undef BUILD
#undef LOADDY
}

extern "C" void kernel_launch(void* const* d_in, const int* in_sizes, int n_in,
                              void* d_out, int out_size, void* d_ws, size_t ws_size,
                              hipStream_t stream)
{
    const float* X = (const float*)d_in[0];
    const float* Y = (const float*)d_in[1];
    float* out = (float*)d_out;
    (void)in_sizes; (void)n_in; (void)out_size; (void)d_ws; (void)ws_size;

    sigker_pipe2<<<dim3(32 * 32), dim3(64), 0, stream>>>(X, Y, out);
}